// Round 11
// baseline (159.499 us; speedup 1.0000x reference)
//
#include <hip/hip_runtime.h>

typedef __attribute__((ext_vector_type(4)))  float f32x4;
typedef __attribute__((ext_vector_type(16))) float f32x16;
typedef __attribute__((ext_vector_type(8)))  short short8;
typedef __attribute__((ext_vector_type(4)))  unsigned short u16x4;
typedef __attribute__((ext_vector_type(4)))  unsigned int u32x4;
typedef __attribute__((ext_vector_type(2)))  unsigned int u32x2;

// float -> bf16, round-to-nearest-even
static __device__ __forceinline__ unsigned short f2bf(float f) {
    unsigned int u = __float_as_uint(f);
    unsigned int r = (u + 0x7FFFu + ((u >> 16) & 1u)) >> 16;
    return (unsigned short)r;
}

#if __has_builtin(__builtin_amdgcn_exp2f)
#define EXP2(x) __builtin_amdgcn_exp2f(x)
#else
#define EXP2(x) exp2f(x)
#endif

// value-semantics permlane32 swap
static __device__ __forceinline__ u32x2 swap32v(unsigned int a, unsigned int b) {
#if __has_builtin(__builtin_amdgcn_permlane32_swap)
    return __builtin_amdgcn_permlane32_swap(a, b, false, false);
#else
    asm("v_permlane32_swap_b32 %0, %1" : "+v"(a), "+v"(b));
    u32x2 r; r[0] = a; r[1] = b; return r;
#endif
}

// 32^-0.5 * log2(e): q-scale with exp2 conversion folded in
#define SCALE2Q 0.25503487756f

// ---------------------------------------------------------------------------
// Kernel 1: pack weights to bf16. W[320][256]: rows 0..31 = scale2q*w_qk(q),
// rows 32..63 = w_qk(k), rows 64..319 = w_v.
// ---------------------------------------------------------------------------
__global__ void prep_w_kernel(const float* __restrict__ wqk,
                              const float* __restrict__ wv,
                              unsigned short* __restrict__ W) {
    int idx = blockIdx.x * 256 + threadIdx.x;
    int o = idx >> 8, c = idx & 255;
    float v;
    if (o < 64) { v = wqk[o * 256 + c]; if (o < 32) v *= SCALE2Q; }
    else        { v = wv[(o - 64) * 256 + c]; }
    W[idx] = f2bf(v);
}

// ---------------------------------------------------------------------------
// Kernel 2: xT[b][s][c] = bf16(x[b][c][s]).  64x64 tiles via LDS.
// ---------------------------------------------------------------------------
__global__ __launch_bounds__(256) void transpose_kernel(
        const float* __restrict__ x, unsigned short* __restrict__ xT) {
    __shared__ unsigned short tile[64][66];
    int b = blockIdx.x & 7;
    int rem = blockIdx.x >> 3;
    int ct = rem >> 6, st = rem & 63;
    int s0 = st * 64, c0 = ct * 64;
    int tid = threadIdx.x;
    int ss = tid & 63, cq = tid >> 6;
#pragma unroll
    for (int p = 0; p < 16; ++p) {
        int cc = p * 4 + cq;
        float v = x[(size_t)(b * 256 + c0 + cc) * 4096 + s0 + ss];
        tile[ss][cc] = f2bf(v);
    }
    __syncthreads();
#pragma unroll
    for (int p = 0; p < 8; ++p) {
        int idx = p * 256 + tid;
        int sr = idx >> 5, jj = idx & 31;
        unsigned int val = *(const unsigned int*)&tile[sr][jj * 2];
        *(unsigned int*)(xT + (size_t)(b * 4096 + s0 + sr) * 256 + c0 + jj * 2) = val;
    }
}

// ---------------------------------------------------------------------------
// Kernel 3: projection GEMM (MFMA 16x16x32, no LDS).
// ---------------------------------------------------------------------------
__global__ __launch_bounds__(256) void proj_kernel(
        const unsigned short* __restrict__ W,    // [320][256]
        const unsigned short* __restrict__ xT,   // [8][4096][256]
        unsigned short* __restrict__ qkT,        // [8][4096][64]
        unsigned short* __restrict__ vbuf) {     // [8][256][4096]
    const int b  = blockIdx.x & 7;
    const int sb = blockIdx.x >> 3;
    const int s0 = sb * 64;
    const int tid = threadIdx.x;
    const int w = tid >> 6, l = tid & 63;
    const int lg = l >> 4, ll = l & 15;
    const size_t xbase = (size_t)b * 4096 * 256;

    f32x4 acc[5][4];
#pragma unroll
    for (int ot = 0; ot < 5; ++ot)
#pragma unroll
        for (int st = 0; st < 4; ++st) acc[ot][st] = (f32x4)0.0f;

    for (int k0 = 0; k0 < 256; k0 += 32) {
        short8 bf[4], af[5];
#pragma unroll
        for (int st = 0; st < 4; ++st)
            bf[st] = *(const short8*)(xT + xbase + (size_t)(s0 + st * 16 + ll) * 256 + k0 + lg * 8);
#pragma unroll
        for (int ot = 0; ot < 5; ++ot)
            af[ot] = *(const short8*)(W + (size_t)(80 * w + ot * 16 + ll) * 256 + k0 + lg * 8);
#pragma unroll
        for (int ot = 0; ot < 5; ++ot)
#pragma unroll
            for (int st = 0; st < 4; ++st)
                acc[ot][st] = __builtin_amdgcn_mfma_f32_16x16x32_bf16(af[ot], bf[st], acc[ot][st], 0, 0, 0);
    }
#pragma unroll
    for (int ot = 0; ot < 5; ++ot) {
        int o0 = 80 * w + ot * 16 + lg * 4;
#pragma unroll
        for (int st = 0; st < 4; ++st) {
            int s = s0 + st * 16 + ll;
            if (o0 < 64) {
                u16x4 pk;
#pragma unroll
                for (int i = 0; i < 4; ++i) pk[i] = f2bf(acc[ot][st][i]);
                *(u16x4*)(qkT + (size_t)b * 4096 * 64 + (size_t)s * 64 + o0) = pk;
            } else {
#pragma unroll
                for (int i = 0; i < 4; ++i)
                    vbuf[(size_t)b * 256 * 4096 + (size_t)(o0 - 64 + i) * 4096 + s] = f2bf(acc[ot][st][i]);
            }
        }
    }
}

// ---------------------------------------------------------------------------
// Kernel 3b: repack V into MFMA B-fragment order.
// vfrag[((b*8 + ct4)*256 + kf16)*64 + l] = short8 of
//   vbuf[b][32*ct4 + (l&31)][16*kf16 + 8*(l>>5) + j], j=0..7.
// ---------------------------------------------------------------------------
__global__ __launch_bounds__(256) void repack_v_kernel(
        const unsigned short* __restrict__ vbuf,   // [8][256][4096]
        unsigned short* __restrict__ vfrag) {      // [8][8][256][64][8]
    int idx = blockIdx.x * 256 + threadIdx.x;      // 4096 blocks
    int l    = idx & 63;
    int kf16 = (idx >> 6) & 255;
    int ct4  = (idx >> 14) & 7;
    int b    = idx >> 17;
    int l31 = l & 31, l5 = l >> 5;
    short8 v = *(const short8*)(vbuf + (size_t)b * 256 * 4096
                                + (size_t)(32 * ct4 + l31) * 4096
                                + 16 * kf16 + 8 * l5);
    *(short8*)(vfrag + (size_t)idx * 8) = v;
}

// ---------------------------------------------------------------------------
// Kernel 3c: repack K into MFMA A-fragment order.
// kfrag[((b*128 + t2)*2 + h)*64 + l] = short8 of
//   qkT[b][32*t2 + (l&31)][32 + 16*h + 8*(l>>5) + j], j=0..7.
// ---------------------------------------------------------------------------
__global__ __launch_bounds__(256) void repack_k_kernel(
        const unsigned short* __restrict__ qkT,    // [8][4096][64]
        unsigned short* __restrict__ kfrag) {      // [8][128][2][64][8]
    int idx = blockIdx.x * 256 + threadIdx.x;      // 512 blocks
    int l  = idx & 63;
    int h  = (idx >> 6) & 1;
    int t2 = (idx >> 7) & 127;
    int b  = idx >> 14;
    int l31 = l & 31, l5 = l >> 5;
    short8 v = *(const short8*)(qkT + (size_t)b * 4096 * 64
                                + (size_t)(32 * t2 + l31) * 64
                                + 32 + 16 * h + 8 * l5);
    *(short8*)(kfrag + (size_t)idx * 8) = v;
}

// ---------------------------------------------------------------------------
// Kernel 4: attention. grid 256 = 8 b x 16 q-tiles(256) x 2 ch-halves;
// 512 thr = 8 waves, 1 block/CU. Wave w: q-rows [s0+32w, +32) x 128 ch.
// All 8 waves read the SAME kfrag/vfrag lines per iter -> L1 filters 7/8.
// In-register softmax (swapped QK, exp2, cvt_pk+permlane), zero barriers.
// V frags: 2-slot rotation (8 live frags) to keep VGPR under the 256 cap.
// ---------------------------------------------------------------------------
__global__ __launch_bounds__(512, 2) void attn_kernel(
        const unsigned short* __restrict__ qkT,   // [8][4096][64] (q|k)
        const unsigned short* __restrict__ kfrag, // [8][128][2][64][8]
        const unsigned short* __restrict__ vfrag, // [8][8][256][64][8]
        const float* __restrict__ x,              // [8][256][4096]
        const float* __restrict__ gamma,
        float* __restrict__ out) {
    __shared__ float lsum_lds[256];

    const int b     = blockIdx.x & 7;        // batch == XCD (L2 pinning)
    const int sb    = (blockIdx.x >> 3) & 15;
    const int chalf = blockIdx.x >> 7;
    const int s0    = sb * 256;
    const int w     = threadIdx.x >> 6;      // 0..7
    const int l     = threadIdx.x & 63;
    const int l5    = l >> 5, l31 = l & 31;

    const size_t qk_base = (size_t)b * 4096 * 64;
    const size_t bx_base = (size_t)b * 256 * 4096;
    const int chbase = 128 * chalf;

    // Q frags (one-time): col = q = s0+32w+l31, k = 8*l5+j (+16)
    const unsigned short* qrow = qkT + qk_base + (size_t)(s0 + 32 * w + l31) * 64;
    const short8 qf0 = *(const short8*)(qrow + 8 * l5);
    const short8 qf1 = *(const short8*)(qrow + 16 + 8 * l5);

    // frag base pointers (frag stride = 512 ushorts = 1 KiB)
    const unsigned short* kfp  = kfrag + (size_t)b * 128 * 2 * 512 + 8 * l;
    const unsigned short* vf0p = vfrag + ((size_t)(b * 8 + chalf * 4 + 0) * 256) * 512 + 8 * l;
    const unsigned short* vf1p = vfrag + ((size_t)(b * 8 + chalf * 4 + 1) * 256) * 512 + 8 * l;
    const unsigned short* vf2p = vfrag + ((size_t)(b * 8 + chalf * 4 + 2) * 256) * 512 + 8 * l;
    const unsigned short* vf3p = vfrag + ((size_t)(b * 8 + chalf * 4 + 3) * 256) * 512 + 8 * l;

    f32x16 acc0 = (f32x16)0.0f, acc1 = (f32x16)0.0f;
    f32x16 acc2 = (f32x16)0.0f, acc3 = (f32x16)0.0f;
    float psum = 0.f;
    const f32x16 z16 = (f32x16)0.0f;

    // K frags for tile 0
    short8 kf00 = *(const short8*)(kfp + 0 * 512);
    short8 kf01 = *(const short8*)(kfp + 1 * 512);
    short8 kf10 = *(const short8*)(kfp + 2 * 512);
    short8 kf11 = *(const short8*)(kfp + 3 * 512);
    // V frag 2-slot rotation: slot A = keyfrag 4t+{0 or 2}, slot B = 4t+{1 or 3}
    short8 vA0 = *(const short8*)(vf0p + 0 * 512);
    short8 vA1 = *(const short8*)(vf1p + 0 * 512);
    short8 vA2 = *(const short8*)(vf2p + 0 * 512);
    short8 vA3 = *(const short8*)(vf3p + 0 * 512);
    short8 vB0 = *(const short8*)(vf0p + 1 * 512);
    short8 vB1 = *(const short8*)(vf1p + 1 * 512);
    short8 vB2 = *(const short8*)(vf2p + 1 * 512);
    short8 vB3 = *(const short8*)(vf3p + 1 * 512);

// exp2 16 regs of DD, pack (cvt_pk), permlane-swap into two PV A-frags.
#define EXPPACK(DD, PLO, PHI)                                                  \
    {                                                                          \
        float e0 = EXP2((DD)[0]),   e1 = EXP2((DD)[1]);                        \
        float e2 = EXP2((DD)[2]),   e3 = EXP2((DD)[3]);                        \
        float e4 = EXP2((DD)[4]),   e5 = EXP2((DD)[5]);                        \
        float e6 = EXP2((DD)[6]),   e7 = EXP2((DD)[7]);                        \
        float e8 = EXP2((DD)[8]),   e9 = EXP2((DD)[9]);                        \
        float e10 = EXP2((DD)[10]), e11 = EXP2((DD)[11]);                      \
        float e12 = EXP2((DD)[12]), e13 = EXP2((DD)[13]);                      \
        float e14 = EXP2((DD)[14]), e15 = EXP2((DD)[15]);                      \
        psum += (((e0 + e1) + (e2 + e3)) + ((e4 + e5) + (e6 + e7)))            \
              + (((e8 + e9) + (e10 + e11)) + ((e12 + e13) + (e14 + e15)));     \
        unsigned int c0, c1, c2, c3;                                           \
        asm("v_cvt_pk_bf16_f32 %0, %1, %2" : "=v"(c0) : "v"(e0), "v"(e1));     \
        asm("v_cvt_pk_bf16_f32 %0, %1, %2" : "=v"(c1) : "v"(e2), "v"(e3));     \
        asm("v_cvt_pk_bf16_f32 %0, %1, %2" : "=v"(c2) : "v"(e4), "v"(e5));     \
        asm("v_cvt_pk_bf16_f32 %0, %1, %2" : "=v"(c3) : "v"(e6), "v"(e7));     \
        u32x2 s0_ = swap32v(c0, c2);                                           \
        u32x2 s1_ = swap32v(c1, c3);                                           \
        u32x4 lo_; lo_[0] = s0_[0]; lo_[1] = s1_[0]; lo_[2] = s0_[1]; lo_[3] = s1_[1]; \
        PLO = __builtin_bit_cast(short8, lo_);                                 \
        unsigned int d0, d1, d2, d3;                                           \
        asm("v_cvt_pk_bf16_f32 %0, %1, %2" : "=v"(d0) : "v"(e8), "v"(e9));     \
        asm("v_cvt_pk_bf16_f32 %0, %1, %2" : "=v"(d1) : "v"(e10), "v"(e11));   \
        asm("v_cvt_pk_bf16_f32 %0, %1, %2" : "=v"(d2) : "v"(e12), "v"(e13));   \
        u32x2 s2_ = swap32v(d0, d2);                                           \
        asm("v_cvt_pk_bf16_f32 %0, %1, %2" : "=v"(d3) : "v"(e14), "v"(e15));   \
        u32x2 s3_ = swap32v(d1, d3);                                           \
        u32x4 hi_; hi_[0] = s2_[0]; hi_[1] = s3_[0]; hi_[2] = s2_[1]; hi_[3] = s3_[1]; \
        PHI = __builtin_bit_cast(short8, hi_);                                 \
    }

#define PV4(PA, V0, V1, V2, V3)                                                \
    acc0 = __builtin_amdgcn_mfma_f32_32x32x16_bf16(PA, V0, acc0, 0, 0, 0);     \
    acc1 = __builtin_amdgcn_mfma_f32_32x32x16_bf16(PA, V1, acc1, 0, 0, 0);     \
    acc2 = __builtin_amdgcn_mfma_f32_32x32x16_bf16(PA, V2, acc2, 0, 0, 0);     \
    acc3 = __builtin_amdgcn_mfma_f32_32x32x16_bf16(PA, V3, acc3, 0, 0, 0);

    for (int t = 0; t < 64; ++t) {
        const int tn = (t + 1) & 63;
        // ---- swapped QK^T: D[key][q] ----
        f32x16 dd0 = __builtin_amdgcn_mfma_f32_32x32x16_bf16(kf00, qf0, z16, 0, 0, 0);
        dd0 = __builtin_amdgcn_mfma_f32_32x32x16_bf16(kf01, qf1, dd0, 0, 0, 0);
        f32x16 dd1 = __builtin_amdgcn_mfma_f32_32x32x16_bf16(kf10, qf0, z16, 0, 0, 0);
        dd1 = __builtin_amdgcn_mfma_f32_32x32x16_bf16(kf11, qf1, dd1, 0, 0, 0);
        // reload K for next tile
        kf00 = *(const short8*)(kfp + (size_t)(4 * tn + 0) * 512);
        kf01 = *(const short8*)(kfp + (size_t)(4 * tn + 1) * 512);
        kf10 = *(const short8*)(kfp + (size_t)(4 * tn + 2) * 512);
        kf11 = *(const short8*)(kfp + (size_t)(4 * tn + 3) * 512);

        short8 pa0, pa1;
        EXPPACK(dd0, pa0, pa1)
        // ks0 (slot A = 4t+0), then refill A <- 4t+2
        PV4(pa0, vA0, vA1, vA2, vA3)
        vA0 = *(const short8*)(vf0p + (size_t)(4 * t + 2) * 512);
        vA1 = *(const short8*)(vf1p + (size_t)(4 * t + 2) * 512);
        vA2 = *(const short8*)(vf2p + (size_t)(4 * t + 2) * 512);
        vA3 = *(const short8*)(vf3p + (size_t)(4 * t + 2) * 512);
        // ks1 (slot B = 4t+1), then refill B <- 4t+3
        PV4(pa1, vB0, vB1, vB2, vB3)
        vB0 = *(const short8*)(vf0p + (size_t)(4 * t + 3) * 512);
        vB1 = *(const short8*)(vf1p + (size_t)(4 * t + 3) * 512);
        vB2 = *(const short8*)(vf2p + (size_t)(4 * t + 3) * 512);
        vB3 = *(const short8*)(vf3p + (size_t)(4 * t + 3) * 512);

        short8 pa2, pa3;
        EXPPACK(dd1, pa2, pa3)
        // ks2 (slot A = 4t+2), refill A <- 4tn+0
        PV4(pa2, vA0, vA1, vA2, vA3)
        vA0 = *(const short8*)(vf0p + (size_t)(4 * tn + 0) * 512);
        vA1 = *(const short8*)(vf1p + (size_t)(4 * tn + 0) * 512);
        vA2 = *(const short8*)(vf2p + (size_t)(4 * tn + 0) * 512);
        vA3 = *(const short8*)(vf3p + (size_t)(4 * tn + 0) * 512);
        // ks3 (slot B = 4t+3), refill B <- 4tn+1
        PV4(pa3, vB0, vB1, vB2, vB3)
        vB0 = *(const short8*)(vf0p + (size_t)(4 * tn + 1) * 512);
        vB1 = *(const short8*)(vf1p + (size_t)(4 * tn + 1) * 512);
        vB2 = *(const short8*)(vf2p + (size_t)(4 * tn + 1) * 512);
        vB3 = *(const short8*)(vf3p + (size_t)(4 * tn + 1) * 512);
    }
#undef EXPPACK
#undef PV4

    // ---- row-sum: lane covers half of q=l31's keys; partner is l^32 ----
    psum += __shfl_xor(psum, 32);
    if (l5 == 0) lsum_lds[32 * w + l31] = psum;
    __syncthreads();

    // ---- epilogue: out = gamma*acc/lsum + x ----
    const float g = gamma[0];
#pragma unroll
    for (int rq = 0; rq < 4; ++rq) {
        f32x4 ls = *(const f32x4*)&lsum_lds[32 * w + 8 * rq + 4 * l5];
        f32x4 gi;
#pragma unroll
        for (int m = 0; m < 4; ++m) gi[m] = g / ls[m];
        const int srow = s0 + 32 * w + 8 * rq + 4 * l5;
#define STORE_CT(ACC, CT)                                                      \
        {                                                                      \
            size_t off = bx_base + (size_t)(chbase + 32 * (CT) + l31) * 4096 + srow; \
            f32x4 xv = *(const f32x4*)(x + off);                               \
            f32x4 o;                                                           \
            o[0] = gi[0] * (ACC)[4 * rq + 0] + xv[0];                          \
            o[1] = gi[1] * (ACC)[4 * rq + 1] + xv[1];                          \
            o[2] = gi[2] * (ACC)[4 * rq + 2] + xv[2];                          \
            o[3] = gi[3] * (ACC)[4 * rq + 3] + xv[3];                          \
            *(f32x4*)(out + off) = o;                                          \
        }
        STORE_CT(acc0, 0)
        STORE_CT(acc1, 1)
        STORE_CT(acc2, 2)
        STORE_CT(acc3, 3)
#undef STORE_CT
    }
}

// ---------------------------------------------------------------------------
extern "C" void kernel_launch(void* const* d_in, const int* in_sizes, int n_in,
                              void* d_out, int out_size, void* d_ws, size_t ws_size,
                              hipStream_t stream) {
    const float* x     = (const float*)d_in[0];
    const float* wqk   = (const float*)d_in[1];
    const float* wv    = (const float*)d_in[2];
    const float* gamma = (const float*)d_in[3];
    float* out = (float*)d_out;

    char* ws = (char*)d_ws;
    unsigned short* W     = (unsigned short*)(ws);                      // 160 KiB
    unsigned short* qkT   = (unsigned short*)(ws + 163840);             // 4 MiB
    unsigned short* xT    = (unsigned short*)(ws + 163840 + 4194304);   // 16 MiB (-> vfrag after proj)
    unsigned short* vbuf  = (unsigned short*)(ws + 163840 + 4194304 + 16777216); // 16 MiB
    unsigned short* kfrag = (unsigned short*)(ws + 163840 + 4194304 + 16777216 + 16777216); // 2 MiB
    unsigned short* vfrag = xT;   // reuse xT region (dead after proj)

    hipLaunchKernelGGL(prep_w_kernel,    dim3(320),  dim3(256), 0, stream, wqk, wv, W);
    hipLaunchKernelGGL(transpose_kernel, dim3(2048), dim3(256), 0, stream, x, xT);
    hipLaunchKernelGGL(proj_kernel,      dim3(512),  dim3(256), 0, stream, W, xT, qkT, vbuf);
    hipLaunchKernelGGL(repack_v_kernel,  dim3(4096), dim3(256), 0, stream, vbuf, vfrag);
    hipLaunchKernelGGL(repack_k_kernel,  dim3(512),  dim3(256), 0, stream, qkT, kfrag);
    hipLaunchKernelGGL(attn_kernel,      dim3(256),  dim3(512), 0, stream, qkT, kfrag, vfrag, x, gamma, out);
}

// Round 12
// 158.497 us; speedup vs baseline: 1.0063x; 1.0063x over previous
//
#include <hip/hip_runtime.h>

typedef __attribute__((ext_vector_type(4)))  float f32x4;
typedef __attribute__((ext_vector_type(16))) float f32x16;
typedef __attribute__((ext_vector_type(8)))  short short8;
typedef __attribute__((ext_vector_type(4)))  unsigned short u16x4;
typedef __attribute__((ext_vector_type(4)))  unsigned int u32x4;
typedef __attribute__((ext_vector_type(2)))  unsigned int u32x2;

// float -> bf16, round-to-nearest-even
static __device__ __forceinline__ unsigned short f2bf(float f) {
    unsigned int u = __float_as_uint(f);
    unsigned int r = (u + 0x7FFFu + ((u >> 16) & 1u)) >> 16;
    return (unsigned short)r;
}

#if __has_builtin(__builtin_amdgcn_exp2f)
#define EXP2(x) __builtin_amdgcn_exp2f(x)
#else
#define EXP2(x) exp2f(x)
#endif

// value-semantics permlane32 swap
static __device__ __forceinline__ u32x2 swap32v(unsigned int a, unsigned int b) {
#if __has_builtin(__builtin_amdgcn_permlane32_swap)
    return __builtin_amdgcn_permlane32_swap(a, b, false, false);
#else
    asm("v_permlane32_swap_b32 %0, %1" : "+v"(a), "+v"(b));
    u32x2 r; r[0] = a; r[1] = b; return r;
#endif
}

// async global->LDS, 16B per lane; dst is wave-uniform base (+ lane*16 in HW)
static __device__ __forceinline__ void glds16(const unsigned short* src,
                                              unsigned short* dst) {
    __builtin_amdgcn_global_load_lds(
        (const __attribute__((address_space(1))) unsigned int*)src,
        (__attribute__((address_space(3))) unsigned int*)dst, 16, 0, 0);
}

// drain all vmem+lds, then raw barrier (memory-clobbered so nothing crosses)
static __device__ __forceinline__ void sync_full() {
    asm volatile("s_waitcnt vmcnt(0) lgkmcnt(0)" ::: "memory");
    __builtin_amdgcn_s_barrier();
    asm volatile("" ::: "memory");
}

// 32^-0.5 * log2(e): q-scale with exp2 conversion folded in
#define SCALE2Q 0.25503487756f

// ---------------------------------------------------------------------------
// Kernel 1: pack weights to bf16. W[320][256]: rows 0..31 = scale2q*w_qk(q),
// rows 32..63 = w_qk(k), rows 64..319 = w_v.
// ---------------------------------------------------------------------------
__global__ void prep_w_kernel(const float* __restrict__ wqk,
                              const float* __restrict__ wv,
                              unsigned short* __restrict__ W) {
    int idx = blockIdx.x * 256 + threadIdx.x;
    int o = idx >> 8, c = idx & 255;
    float v;
    if (o < 64) { v = wqk[o * 256 + c]; if (o < 32) v *= SCALE2Q; }
    else        { v = wv[(o - 64) * 256 + c]; }
    W[idx] = f2bf(v);
}

// ---------------------------------------------------------------------------
// Kernel 2: xT[b][s][c] = bf16(x[b][c][s]).  64x64 tiles via LDS.
// ---------------------------------------------------------------------------
__global__ __launch_bounds__(256) void transpose_kernel(
        const float* __restrict__ x, unsigned short* __restrict__ xT) {
    __shared__ unsigned short tile[64][66];
    int b = blockIdx.x & 7;
    int rem = blockIdx.x >> 3;
    int ct = rem >> 6, st = rem & 63;
    int s0 = st * 64, c0 = ct * 64;
    int tid = threadIdx.x;
    int ss = tid & 63, cq = tid >> 6;
#pragma unroll
    for (int p = 0; p < 16; ++p) {
        int cc = p * 4 + cq;
        float v = x[(size_t)(b * 256 + c0 + cc) * 4096 + s0 + ss];
        tile[ss][cc] = f2bf(v);
    }
    __syncthreads();
#pragma unroll
    for (int p = 0; p < 8; ++p) {
        int idx = p * 256 + tid;
        int sr = idx >> 5, jj = idx & 31;
        unsigned int val = *(const unsigned int*)&tile[sr][jj * 2];
        *(unsigned int*)(xT + (size_t)(b * 4096 + s0 + sr) * 256 + c0 + jj * 2) = val;
    }
}

// ---------------------------------------------------------------------------
// Kernel 3: projection GEMM (MFMA 16x16x32, no LDS).
// ---------------------------------------------------------------------------
__global__ __launch_bounds__(256) void proj_kernel(
        const unsigned short* __restrict__ W,    // [320][256]
        const unsigned short* __restrict__ xT,   // [8][4096][256]
        unsigned short* __restrict__ qkT,        // [8][4096][64]
        unsigned short* __restrict__ vbuf) {     // [8][256][4096]
    const int b  = blockIdx.x & 7;
    const int sb = blockIdx.x >> 3;
    const int s0 = sb * 64;
    const int tid = threadIdx.x;
    const int w = tid >> 6, l = tid & 63;
    const int lg = l >> 4, ll = l & 15;
    const size_t xbase = (size_t)b * 4096 * 256;

    f32x4 acc[5][4];
#pragma unroll
    for (int ot = 0; ot < 5; ++ot)
#pragma unroll
        for (int st = 0; st < 4; ++st) acc[ot][st] = (f32x4)0.0f;

    for (int k0 = 0; k0 < 256; k0 += 32) {
        short8 bf[4], af[5];
#pragma unroll
        for (int st = 0; st < 4; ++st)
            bf[st] = *(const short8*)(xT + xbase + (size_t)(s0 + st * 16 + ll) * 256 + k0 + lg * 8);
#pragma unroll
        for (int ot = 0; ot < 5; ++ot)
            af[ot] = *(const short8*)(W + (size_t)(80 * w + ot * 16 + ll) * 256 + k0 + lg * 8);
#pragma unroll
        for (int ot = 0; ot < 5; ++ot)
#pragma unroll
            for (int st = 0; st < 4; ++st)
                acc[ot][st] = __builtin_amdgcn_mfma_f32_16x16x32_bf16(af[ot], bf[st], acc[ot][st], 0, 0, 0);
    }
#pragma unroll
    for (int ot = 0; ot < 5; ++ot) {
        int o0 = 80 * w + ot * 16 + lg * 4;
#pragma unroll
        for (int st = 0; st < 4; ++st) {
            int s = s0 + st * 16 + ll;
            if (o0 < 64) {
                u16x4 pk;
#pragma unroll
                for (int i = 0; i < 4; ++i) pk[i] = f2bf(acc[ot][st][i]);
                *(u16x4*)(qkT + (size_t)b * 4096 * 64 + (size_t)s * 64 + o0) = pk;
            } else {
#pragma unroll
                for (int i = 0; i < 4; ++i)
                    vbuf[(size_t)b * 256 * 4096 + (size_t)(o0 - 64 + i) * 4096 + s] = f2bf(acc[ot][st][i]);
            }
        }
    }
}

// ---------------------------------------------------------------------------
// Kernel 3b: repack V into MFMA B-fragment order.
// vfrag[((b*8 + ct4)*256 + kf16)*64 + l] = short8 of
//   vbuf[b][32*ct4 + (l&31)][16*kf16 + 8*(l>>5) + j], j=0..7.
// ---------------------------------------------------------------------------
__global__ __launch_bounds__(256) void repack_v_kernel(
        const unsigned short* __restrict__ vbuf,   // [8][256][4096]
        unsigned short* __restrict__ vfrag) {      // [8][8][256][64][8]
    int idx = blockIdx.x * 256 + threadIdx.x;      // 4096 blocks
    int l    = idx & 63;
    int kf16 = (idx >> 6) & 255;
    int ct4  = (idx >> 14) & 7;
    int b    = idx >> 17;
    int l31 = l & 31, l5 = l >> 5;
    short8 v = *(const short8*)(vbuf + (size_t)b * 256 * 4096
                                + (size_t)(32 * ct4 + l31) * 4096
                                + 16 * kf16 + 8 * l5);
    *(short8*)(vfrag + (size_t)idx * 8) = v;
}

// ---------------------------------------------------------------------------
// Kernel 3c: repack K into MFMA A-fragment order.
// kfrag[((b*128 + t2)*2 + h)*64 + l] = short8 of
//   qkT[b][32*t2 + (l&31)][32 + 16*h + 8*(l>>5) + j], j=0..7.
// ---------------------------------------------------------------------------
__global__ __launch_bounds__(256) void repack_k_kernel(
        const unsigned short* __restrict__ qkT,    // [8][4096][64]
        unsigned short* __restrict__ kfrag) {      // [8][128][2][64][8]
    int idx = blockIdx.x * 256 + threadIdx.x;      // 512 blocks
    int l  = idx & 63;
    int h  = (idx >> 6) & 1;
    int t2 = (idx >> 7) & 127;
    int b  = idx >> 14;
    int l31 = l & 31, l5 = l >> 5;
    short8 v = *(const short8*)(qkT + (size_t)b * 4096 * 64
                                + (size_t)(32 * t2 + l31) * 64
                                + 32 + 16 * h + 8 * l5);
    *(short8*)(kfrag + (size_t)idx * 8) = v;
}

// ---------------------------------------------------------------------------
// Kernel 4: attention. grid 256 = 8 b x 16 q-tiles(256) x 2 ch-halves;
// 512 thr = 8 waves, 1 block/CU. Wave w: q-rows [s0+32w,+32) x 128 ch.
// V tile (16 KB/iter, same for all waves) staged ONCE via global_load_lds
// into double-buffered LDS (each wave DMAs 2 KB); consumers ds_read_b128.
// K frags via L1 (rolling reload). In-register softmax (swapped QK, exp2,
// cvt_pk+permlane). One vmcnt(0)+lgkm(0)+barrier per iter.
// ---------------------------------------------------------------------------
__global__ __launch_bounds__(512, 1) void attn_kernel(
        const unsigned short* __restrict__ qkT,   // [8][4096][64] (q|k)
        const unsigned short* __restrict__ kfrag, // [8][128][2][64][8]
        const unsigned short* __restrict__ vfrag, // [8][8][256][64][8]
        const float* __restrict__ x,              // [8][256][4096]
        const float* __restrict__ gamma,
        float* __restrict__ out) {
    __shared__ unsigned short vlds[2][16][64][8];  // 32 KiB: [buf][ct*4+ks][lane][8]
    __shared__ float lsum_lds[256];

    const int b     = blockIdx.x & 7;        // batch == XCD (L2 pinning)
    const int sb    = (blockIdx.x >> 3) & 15;
    const int chalf = blockIdx.x >> 7;
    const int s0    = sb * 256;
    const int w     = threadIdx.x >> 6;      // 0..7
    const int l     = threadIdx.x & 63;
    const int l5    = l >> 5, l31 = l & 31;

    const size_t qk_base = (size_t)b * 4096 * 64;
    const size_t bx_base = (size_t)b * 256 * 4096;
    const int chbase = 128 * chalf;

    // Q frags (one-time): col = q = s0+32w+l31, k = 8*l5+j (+16)
    const unsigned short* qrow = qkT + qk_base + (size_t)(s0 + 32 * w + l31) * 64;
    const short8 qf0 = *(const short8*)(qrow + 8 * l5);
    const short8 qf1 = *(const short8*)(qrow + 16 + 8 * l5);

    // K frag pointer (frag stride = 512 ushorts = 1 KiB)
    const unsigned short* kfp = kfrag + (size_t)b * 128 * 2 * 512 + 8 * l;

    // V stage sources: this wave stages chunks c0_=2w, c1_=2w+1 of the 16-chunk
    // tile; chunk c -> frag (ct4 = c>>2, ks = c&3); frag idx = ct4*256 + 4t + ks
    const unsigned short* vfb = vfrag + (size_t)(b * 8 + chalf * 4) * 256 * 512 + 8 * l;
    const int c0_ = 2 * w, c1_ = 2 * w + 1;
    const unsigned short* src0 = vfb + (size_t)((c0_ >> 2) * 256 + (c0_ & 3)) * 512;
    const unsigned short* src1 = vfb + (size_t)((c1_ >> 2) * 256 + (c1_ & 3)) * 512;

    f32x16 acc0 = (f32x16)0.0f, acc1 = (f32x16)0.0f;
    f32x16 acc2 = (f32x16)0.0f, acc3 = (f32x16)0.0f;
    float psum = 0.f;
    const f32x16 z16 = (f32x16)0.0f;

    // prologue: stage V tile 0 into buf 0; load K frags for tile 0
    glds16(src0, &vlds[0][c0_][0][0]);
    glds16(src1, &vlds[0][c1_][0][0]);
    short8 kf00 = *(const short8*)(kfp + 0 * 512);
    short8 kf01 = *(const short8*)(kfp + 1 * 512);
    short8 kf10 = *(const short8*)(kfp + 2 * 512);
    short8 kf11 = *(const short8*)(kfp + 3 * 512);
    sync_full();

// exp2 16 regs of DD, pack (cvt_pk), permlane-swap into two PV A-frags.
#define EXPPACK(DD, PLO, PHI)                                                  \
    {                                                                          \
        float e0 = EXP2((DD)[0]),   e1 = EXP2((DD)[1]);                        \
        float e2 = EXP2((DD)[2]),   e3 = EXP2((DD)[3]);                        \
        float e4 = EXP2((DD)[4]),   e5 = EXP2((DD)[5]);                        \
        float e6 = EXP2((DD)[6]),   e7 = EXP2((DD)[7]);                        \
        float e8 = EXP2((DD)[8]),   e9 = EXP2((DD)[9]);                        \
        float e10 = EXP2((DD)[10]), e11 = EXP2((DD)[11]);                      \
        float e12 = EXP2((DD)[12]), e13 = EXP2((DD)[13]);                      \
        float e14 = EXP2((DD)[14]), e15 = EXP2((DD)[15]);                      \
        psum += (((e0 + e1) + (e2 + e3)) + ((e4 + e5) + (e6 + e7)))            \
              + (((e8 + e9) + (e10 + e11)) + ((e12 + e13) + (e14 + e15)));     \
        unsigned int c0, c1, c2, c3;                                           \
        asm("v_cvt_pk_bf16_f32 %0, %1, %2" : "=v"(c0) : "v"(e0), "v"(e1));     \
        asm("v_cvt_pk_bf16_f32 %0, %1, %2" : "=v"(c1) : "v"(e2), "v"(e3));     \
        asm("v_cvt_pk_bf16_f32 %0, %1, %2" : "=v"(c2) : "v"(e4), "v"(e5));     \
        asm("v_cvt_pk_bf16_f32 %0, %1, %2" : "=v"(c3) : "v"(e6), "v"(e7));     \
        u32x2 s0_ = swap32v(c0, c2);                                           \
        u32x2 s1_ = swap32v(c1, c3);                                           \
        u32x4 lo_; lo_[0] = s0_[0]; lo_[1] = s1_[0]; lo_[2] = s0_[1]; lo_[3] = s1_[1]; \
        PLO = __builtin_bit_cast(short8, lo_);                                 \
        unsigned int d0, d1, d2, d3;                                           \
        asm("v_cvt_pk_bf16_f32 %0, %1, %2" : "=v"(d0) : "v"(e8), "v"(e9));     \
        asm("v_cvt_pk_bf16_f32 %0, %1, %2" : "=v"(d1) : "v"(e10), "v"(e11));   \
        asm("v_cvt_pk_bf16_f32 %0, %1, %2" : "=v"(d2) : "v"(e12), "v"(e13));   \
        u32x2 s2_ = swap32v(d0, d2);                                           \
        asm("v_cvt_pk_bf16_f32 %0, %1, %2" : "=v"(d3) : "v"(e14), "v"(e15));   \
        u32x2 s3_ = swap32v(d1, d3);                                           \
        u32x4 hi_; hi_[0] = s2_[0]; hi_[1] = s3_[0]; hi_[2] = s2_[1]; hi_[3] = s3_[1]; \
        PHI = __builtin_bit_cast(short8, hi_);                                 \
    }

#define PV4(PA, V0, V1, V2, V3)                                                \
    acc0 = __builtin_amdgcn_mfma_f32_32x32x16_bf16(PA, V0, acc0, 0, 0, 0);     \
    acc1 = __builtin_amdgcn_mfma_f32_32x32x16_bf16(PA, V1, acc1, 0, 0, 0);     \
    acc2 = __builtin_amdgcn_mfma_f32_32x32x16_bf16(PA, V2, acc2, 0, 0, 0);     \
    acc3 = __builtin_amdgcn_mfma_f32_32x32x16_bf16(PA, V3, acc3, 0, 0, 0);

    for (int t = 0; t < 64; ++t) {
        const int pb = t & 1;
        const int tn = (t + 1) & 63;

        // ---- issue stage of V tile t+1 into buf pb^1 (in flight all iter) --
        glds16(src0 + (size_t)(4 * tn) * 512, &vlds[pb ^ 1][c0_][0][0]);
        glds16(src1 + (size_t)(4 * tn) * 512, &vlds[pb ^ 1][c1_][0][0]);

        // ---- swapped QK^T: D[key][q] ----
        f32x16 dd0 = __builtin_amdgcn_mfma_f32_32x32x16_bf16(kf00, qf0, z16, 0, 0, 0);
        dd0 = __builtin_amdgcn_mfma_f32_32x32x16_bf16(kf01, qf1, dd0, 0, 0, 0);
        f32x16 dd1 = __builtin_amdgcn_mfma_f32_32x32x16_bf16(kf10, qf0, z16, 0, 0, 0);
        dd1 = __builtin_amdgcn_mfma_f32_32x32x16_bf16(kf11, qf1, dd1, 0, 0, 0);
        // reload K for next tile (L1; same line for all 8 waves)
        kf00 = *(const short8*)(kfp + (size_t)(4 * tn + 0) * 512);
        kf01 = *(const short8*)(kfp + (size_t)(4 * tn + 1) * 512);
        kf10 = *(const short8*)(kfp + (size_t)(4 * tn + 2) * 512);
        kf11 = *(const short8*)(kfp + (size_t)(4 * tn + 3) * 512);

        // ---- softmax numerators in-register ----
        short8 pa0, pa1, pa2, pa3;
        EXPPACK(dd0, pa0, pa1)
        EXPPACK(dd1, pa2, pa3)

        // ---- PV from LDS buf[pb], 2-slot rotation ----
        short8 va0 = *(const short8*)&vlds[pb][0][l][0];   // ct0..3, ks=0
        short8 va1 = *(const short8*)&vlds[pb][4][l][0];
        short8 va2 = *(const short8*)&vlds[pb][8][l][0];
        short8 va3 = *(const short8*)&vlds[pb][12][l][0];
        short8 vb0 = *(const short8*)&vlds[pb][1][l][0];   // ks=1
        short8 vb1 = *(const short8*)&vlds[pb][5][l][0];
        short8 vb2 = *(const short8*)&vlds[pb][9][l][0];
        short8 vb3 = *(const short8*)&vlds[pb][13][l][0];
        PV4(pa0, va0, va1, va2, va3)
        va0 = *(const short8*)&vlds[pb][2][l][0];          // ks=2
        va1 = *(const short8*)&vlds[pb][6][l][0];
        va2 = *(const short8*)&vlds[pb][10][l][0];
        va3 = *(const short8*)&vlds[pb][14][l][0];
        PV4(pa1, vb0, vb1, vb2, vb3)
        vb0 = *(const short8*)&vlds[pb][3][l][0];          // ks=3
        vb1 = *(const short8*)&vlds[pb][7][l][0];
        vb2 = *(const short8*)&vlds[pb][11][l][0];
        vb3 = *(const short8*)&vlds[pb][15][l][0];
        PV4(pa2, va0, va1, va2, va3)
        PV4(pa3, vb0, vb1, vb2, vb3)

        // ---- drain stage(t+1) + all ds_reads, then barrier ----
        sync_full();
    }
#undef EXPPACK
#undef PV4

    // ---- row-sum: lane covers half of q=l31's keys; partner is l^32 ----
    psum += __shfl_xor(psum, 32);
    if (l5 == 0) lsum_lds[32 * w + l31] = psum;
    __syncthreads();

    // ---- epilogue: out = gamma*acc/lsum + x ----
    const float g = gamma[0];
#pragma unroll
    for (int rq = 0; rq < 4; ++rq) {
        f32x4 ls = *(const f32x4*)&lsum_lds[32 * w + 8 * rq + 4 * l5];
        f32x4 gi;
#pragma unroll
        for (int m = 0; m < 4; ++m) gi[m] = g / ls[m];
        const int srow = s0 + 32 * w + 8 * rq + 4 * l5;
#define STORE_CT(ACC, CT)                                                      \
        {                                                                      \
            size_t off = bx_base + (size_t)(chbase + 32 * (CT) + l31) * 4096 + srow; \
            f32x4 xv = *(const f32x4*)(x + off);                               \
            f32x4 o;                                                           \
            o[0] = gi[0] * (ACC)[4 * rq + 0] + xv[0];                          \
            o[1] = gi[1] * (ACC)[4 * rq + 1] + xv[1];                          \
            o[2] = gi[2] * (ACC)[4 * rq + 2] + xv[2];                          \
            o[3] = gi[3] * (ACC)[4 * rq + 3] + xv[3];                          \
            *(f32x4*)(out + off) = o;                                          \
        }
        STORE_CT(acc0, 0)
        STORE_CT(acc1, 1)
        STORE_CT(acc2, 2)
        STORE_CT(acc3, 3)
#undef STORE_CT
    }
}

// ---------------------------------------------------------------------------
extern "C" void kernel_launch(void* const* d_in, const int* in_sizes, int n_in,
                              void* d_out, int out_size, void* d_ws, size_t ws_size,
                              hipStream_t stream) {
    const float* x     = (const float*)d_in[0];
    const float* wqk   = (const float*)d_in[1];
    const float* wv    = (const float*)d_in[2];
    const float* gamma = (const float*)d_in[3];
    float* out = (float*)d_out;

    char* ws = (char*)d_ws;
    unsigned short* W     = (unsigned short*)(ws);                      // 160 KiB
    unsigned short* qkT   = (unsigned short*)(ws + 163840);             // 4 MiB
    unsigned short* xT    = (unsigned short*)(ws + 163840 + 4194304);   // 16 MiB (-> vfrag after proj)
    unsigned short* vbuf  = (unsigned short*)(ws + 163840 + 4194304 + 16777216); // 16 MiB
    unsigned short* kfrag = (unsigned short*)(ws + 163840 + 4194304 + 16777216 + 16777216); // 2 MiB
    unsigned short* vfrag = xT;   // reuse xT region (dead after proj)

    hipLaunchKernelGGL(prep_w_kernel,    dim3(320),  dim3(256), 0, stream, wqk, wv, W);
    hipLaunchKernelGGL(transpose_kernel, dim3(2048), dim3(256), 0, stream, x, xT);
    hipLaunchKernelGGL(proj_kernel,      dim3(512),  dim3(256), 0, stream, W, xT, qkT, vbuf);
    hipLaunchKernelGGL(repack_v_kernel,  dim3(4096), dim3(256), 0, stream, vbuf, vfrag);
    hipLaunchKernelGGL(repack_k_kernel,  dim3(512),  dim3(256), 0, stream, qkT, kfrag);
    hipLaunchKernelGGL(attn_kernel,      dim3(256),  dim3(512), 0, stream, qkT, kfrag, vfrag, x, gamma, out);
}